// Round 3
// baseline (705.064 us; speedup 1.0000x reference)
//
#include <hip/hip_runtime.h>
#include <math.h>

// Problem constants
constexpr int B_   = 16;
constexpr int DIM  = 1024;
constexpr int T_   = 2048;
constexpr int NFFT = 1024;
constexpr int HOP  = 256;
constexpr int NBINS = 513;
constexpr int M_TOT = B_ * T_;            // 32768
constexpr int OUT_LEN = HOP * (T_ - 1);   // 524032
constexpr int NPAD = 640;                 // padded rows per head region (W pack layout)
constexpr int NGEMM = 512;                // rows computed by the head GEMM (bin 512 separate)
constexpr int NROWS = 2 * NPAD;           // 1280 packed W rows
constexpr int KSPEC = 1056;               // spec/basis K (513 cos + pad + 512 sin + pad)
constexpr float TWO_PI_F = 6.28318530717958647692f;
constexpr float PI_F = 3.14159265358979323846f;

typedef _Float16 h8 __attribute__((ext_vector_type(8)));
typedef float fv16 __attribute__((ext_vector_type(16)));

#define GLOAD_LDS16(g, l) __builtin_amdgcn_global_load_lds(                  \
    (const __attribute__((address_space(1))) void*)(g),                      \
    (__attribute__((address_space(3))) void*)(l), 16, 0, 0)

// XOR swizzle of 16B groups within a 64B LDS row: kills the 8-way bank
// aliasing of row-stride-64B fragment reads.
__device__ __forceinline__ int xorf(int row) { return (row & 3) ^ ((row >> 2) & 3); }

// ---------------------------------------------------------------------------
// Zero the bin-512 accumulators (2 * B_*T_ floats, contiguous)
// ---------------------------------------------------------------------------
__global__ void k_zero512(float* __restrict__ p) {
    p[blockIdx.x * 256 + threadIdx.x] = 0.f;
}

// ---------------------------------------------------------------------------
// Convert x [b][k][t] f32 -> xT hi/lo [b][t][k] f16 (64x64 tile transpose).
// Fused: bin-512 partial dot products (exact f32) via atomicAdd.
// ---------------------------------------------------------------------------
__global__ __launch_bounds__(256) void k_convert_x(
    const float* __restrict__ x, const float* __restrict__ Wm,
    const float* __restrict__ Wp,
    _Float16* __restrict__ xh, _Float16* __restrict__ xl,
    float* __restrict__ d512m, float* __restrict__ d512p) {
    __shared__ float tile[64][65];
    const int tid = threadIdx.x;
    const int k0 = blockIdx.x * 64;
    const int t0 = blockIdx.y * 64;
    const int b  = blockIdx.z;
    {
        int kr = tid >> 2;
        int tq = (tid & 3) * 16;
        const float* src = x + ((size_t)(b * DIM + k0 + kr)) * T_ + t0 + tq;
        #pragma unroll
        for (int i = 0; i < 4; ++i) {
            float4 v = *(const float4*)(src + i * 4);
            tile[kr][tq + i * 4 + 0] = v.x;
            tile[kr][tq + i * 4 + 1] = v.y;
            tile[kr][tq + i * 4 + 2] = v.z;
            tile[kr][tq + i * 4 + 3] = v.w;
        }
    }
    __syncthreads();
    {
        int tr = tid >> 2;
        int kq = (tid & 3) * 16;
        const float* wm5 = Wm + (size_t)512 * DIM + k0 + kq;
        const float* wp5 = Wp + (size_t)512 * DIM + k0 + kq;
        _Float16 hv[16], lv[16];
        float pm = 0.f, pp = 0.f;
        #pragma unroll
        for (int i = 0; i < 16; ++i) {
            float w = tile[kq + i][tr];
            _Float16 h = (_Float16)w;
            hv[i] = h;
            lv[i] = (_Float16)(w - (float)h);
            pm += w * wm5[i];
            pp += w * wp5[i];
        }
        size_t base = ((size_t)(b * T_ + t0 + tr)) * DIM + k0 + kq;
        *(h8*)(xh + base)     = *(const h8*)&hv[0];
        *(h8*)(xh + base + 8) = *(const h8*)&hv[8];
        *(h8*)(xl + base)     = *(const h8*)&lv[0];
        *(h8*)(xl + base + 8) = *(const h8*)&lv[8];
        // reduce the 4 k-quarters for this t-row (adjacent lanes)
        pm += __shfl_xor(pm, 1); pm += __shfl_xor(pm, 2);
        pp += __shfl_xor(pp, 1); pp += __shfl_xor(pp, 2);
        if ((tid & 3) == 0) {
            atomicAdd(&d512m[b * T_ + t0 + tr], pm);
            atomicAdd(&d512p[b * T_ + t0 + tr], pp);
        }
    }
}

// ---------------------------------------------------------------------------
// Pack W: rows 0..512 = W_mag, 513..639 zero, 640..1152 = W_phase, rest zero
// ---------------------------------------------------------------------------
__global__ void k_pack_w(const float* __restrict__ Wm, const float* __restrict__ Wp,
                         _Float16* __restrict__ Wh, _Float16* __restrict__ Wl) {
    int idx = blockIdx.x * 256 + threadIdx.x;
    if (idx >= NROWS * DIM) return;
    int n = idx >> 10, k = idx & 1023;
    float w = 0.f;
    if (n < NBINS) w = Wm[(size_t)n * DIM + k];
    else if (n >= NPAD && n < NPAD + NBINS) w = Wp[(size_t)(n - NPAD) * DIM + k];
    _Float16 h = (_Float16)w;
    Wh[idx] = h;
    Wl[idx] = (_Float16)(w - (float)h);
}

__global__ void k_pack_bias(const float* __restrict__ bm, const float* __restrict__ bp,
                            float* __restrict__ biasp) {
    int n = blockIdx.x * 256 + threadIdx.x;
    if (n >= NROWS) return;
    float v = 0.f;
    if (n < NBINS) v = bm[n];
    else if (n >= NPAD && n < NPAD + NBINS) v = bp[n - NPAD];
    biasp[n] = v;
}

// ---------------------------------------------------------------------------
// basisT[j][r] f16, stride KSPEC. Includes 1/N, irfft weights, Hann window.
// ---------------------------------------------------------------------------
__global__ void k_basisT(_Float16* __restrict__ basisT) {
    int idx = blockIdx.x * 256 + threadIdx.x;
    if (idx >= NFFT * KSPEC) return;
    int j = idx / KSPEC;
    int r = idx - j * KSPEC;
    float win = 0.5f * (1.0f - __cosf((float)j * (TWO_PI_F / NFFT)));
    float val = 0.f;
    if (r < NBINS) {
        int k = r;
        int m = (k * j) & (NFFT - 1);
        float s, c;
        __sincosf((float)m * (TWO_PI_F / NFFT), &s, &c);
        float w = (k == 0 || k == NFFT / 2) ? 1.0f : 2.0f;
        val = w * (1.0f / NFFT) * c * win;
    } else if (r >= 528 && r < 1040) {
        int k = r - 528;
        int m = (k * j) & (NFFT - 1);
        float s, c;
        __sincosf((float)m * (TWO_PI_F / NFFT), &s, &c);
        val = -2.0f * (1.0f / NFFT) * s * win;
    }
    basisT[idx] = (_Float16)val;
}

// ---------------------------------------------------------------------------
// Head GEMMs v3: W (L2-hot, block-reused) via LDS double-buffer; x (streamed
// once) read global->VGPR directly with 1-step register prefetch. This halves+
// LDS traffic per MFMA (the R2 bottleneck: 33 FLOP/LDS-byte ~ LDS-BW-bound).
// One __syncthreads per k-step; prefetch issued before compute so its latency
// hides under ds_read+MFMA.
//   n-region 0..3: mag rows 0..511, 1-pass hi*hi, epilogue exp(clip) -> f16
//   n-region 4..7: phase rows, 3-pass, epilogue clip -> f32
// ---------------------------------------------------------------------------
__global__ __launch_bounds__(256) void k_gemm_heads3(
    const _Float16* __restrict__ Wh, const _Float16* __restrict__ Wl,
    const _Float16* __restrict__ xh, const _Float16* __restrict__ xl,
    const float* __restrict__ biasp,
    _Float16* __restrict__ bufmag, float* __restrict__ bufph) {
    __shared__ _Float16 sA[2 * 8192];   // [cur][{hi,lo}][4096]
    const int tid = threadIdx.x;
    const int lane = tid & 63;
    const int wv = tid >> 6;
    const int wr = wv >> 1, wc = wv & 1;
    const int h = lane >> 5, r5 = lane & 31;
    const int L = blockIdx.x;
    const int xcd = L & 7;
    const int idx = L >> 3;
    const int nt_g = idx & 7;             // 0..3 mag, 4..7 phase
    const int m_tile = (idx >> 3) * 8 + xcd;
    const bool is_mag = nt_g < 4;
    const int n0 = (is_mag ? 0 : NPAD) + (nt_g & 3) * 128;
    const int m0 = m_tile * 128;
    const int bb = m0 >> 11;
    const int t0 = m0 & (T_ - 1);
    const size_t xbase = ((size_t)(bb * T_ + t0)) * DIM;

    // A (W) staging: per-wave quarter, pre-swizzled source
    const int cid0 = wv * 128 + lane, cid1 = cid0 + 64;
    const int ar0 = cid0 >> 2, g0 = (cid0 & 3) ^ xorf(ar0);
    const int ar1 = cid1 >> 2, g1 = (cid1 & 3) ^ xorf(ar1);
    const size_t a0 = ((size_t)(n0 + ar0) << 10) + g0 * 8;
    const size_t a1 = ((size_t)(n0 + ar1) << 10) + g1 * 8;
    const int pA = wv * 1024;

    const int xv = xorf(r5);
    int offA[2][2];
    #pragma unroll
    for (int mt = 0; mt < 2; ++mt)
        #pragma unroll
        for (int s = 0; s < 2; ++s)
            offA[mt][s] = (wr * 64 + mt * 32 + r5) * 32 + (((s << 1) | h) ^ xv) * 8;

    // B (x) direct fragment addresses: row = wc*64+nt*32+r5, chunk = ((s<<1)|h)*8
    size_t bD[2][2];
    #pragma unroll
    for (int nt = 0; nt < 2; ++nt)
        #pragma unroll
        for (int s = 0; s < 2; ++s)
            bD[nt][s] = xbase + ((size_t)(wc * 64 + nt * 32 + r5) << 10)
                        + (((s << 1) | h) << 3);

    fv16 acc[2][2];
    fv16 zero = {0,0,0,0,0,0,0,0,0,0,0,0,0,0,0,0};
    #pragma unroll
    for (int i = 0; i < 2; ++i)
        #pragma unroll
        for (int j = 0; j < 2; ++j) acc[i][j] = zero;

    if (is_mag) {
        // ---------------- mag flavor: 1-pass hi*hi ----------------
        h8 bHc[2][2], bHn[2][2];
        GLOAD_LDS16(Wh + a0, sA + pA);
        GLOAD_LDS16(Wh + a1, sA + pA + 512);
        #pragma unroll
        for (int nt = 0; nt < 2; ++nt)
            #pragma unroll
            for (int s = 0; s < 2; ++s)
                bHc[nt][s] = *(const h8*)(xh + bD[nt][s]);
        __syncthreads();
        int co = 0;
        for (int k0 = 0; k0 < DIM; k0 += 32) {
            const int nk = k0 + 32;
            const int cn = co ^ 8192;
            if (nk < DIM) {
                GLOAD_LDS16(Wh + a0 + nk, sA + cn + pA);
                GLOAD_LDS16(Wh + a1 + nk, sA + cn + pA + 512);
                #pragma unroll
                for (int nt = 0; nt < 2; ++nt)
                    #pragma unroll
                    for (int s = 0; s < 2; ++s)
                        bHn[nt][s] = *(const h8*)(xh + bD[nt][s] + nk);
            }
            h8 aH[2][2];
            #pragma unroll
            for (int mt = 0; mt < 2; ++mt)
                #pragma unroll
                for (int s = 0; s < 2; ++s)
                    aH[mt][s] = *(const h8*)&sA[co + offA[mt][s]];
            #pragma unroll
            for (int mt = 0; mt < 2; ++mt)
                #pragma unroll
                for (int nt = 0; nt < 2; ++nt)
                    #pragma unroll
                    for (int s = 0; s < 2; ++s)
                        acc[mt][nt] = __builtin_amdgcn_mfma_f32_32x32x16_f16(
                            aH[mt][s], bHc[nt][s], acc[mt][nt], 0, 0, 0);
            __syncthreads();
            if (nk < DIM) {
                #pragma unroll
                for (int nt = 0; nt < 2; ++nt)
                    #pragma unroll
                    for (int s = 0; s < 2; ++s)
                        bHc[nt][s] = bHn[nt][s];
            }
            co = cn;
        }
        #pragma unroll
        for (int mt = 0; mt < 2; ++mt)
            #pragma unroll
            for (int nt = 0; nt < 2; ++nt) {
                int col = m0 + wc * 64 + nt * 32 + r5;
                #pragma unroll
                for (int reg = 0; reg < 16; ++reg) {
                    int rl = (reg & 3) + 8 * (reg >> 2) + 4 * h;
                    int n = n0 + wr * 64 + mt * 32 + rl;
                    float val = acc[mt][nt][reg] + biasp[n];
                    val = fminf(fmaxf(val, -10.f), 10.f);
                    bufmag[(size_t)n * M_TOT + col] = (_Float16)expf(val);
                }
            }
    } else {
        // ---------------- phase flavor: 3-pass hi/lo ----------------
        h8 bHc[2][2], bLc[2][2], bHn[2][2], bLn[2][2];
        GLOAD_LDS16(Wh + a0, sA + pA);
        GLOAD_LDS16(Wh + a1, sA + pA + 512);
        GLOAD_LDS16(Wl + a0, sA + 4096 + pA);
        GLOAD_LDS16(Wl + a1, sA + 4096 + pA + 512);
        #pragma unroll
        for (int nt = 0; nt < 2; ++nt)
            #pragma unroll
            for (int s = 0; s < 2; ++s) {
                bHc[nt][s] = *(const h8*)(xh + bD[nt][s]);
                bLc[nt][s] = *(const h8*)(xl + bD[nt][s]);
            }
        __syncthreads();
        int co = 0;
        for (int k0 = 0; k0 < DIM; k0 += 32) {
            const int nk = k0 + 32;
            const int cn = co ^ 8192;
            if (nk < DIM) {
                GLOAD_LDS16(Wh + a0 + nk, sA + cn + pA);
                GLOAD_LDS16(Wh + a1 + nk, sA + cn + pA + 512);
                GLOAD_LDS16(Wl + a0 + nk, sA + cn + 4096 + pA);
                GLOAD_LDS16(Wl + a1 + nk, sA + cn + 4096 + pA + 512);
                #pragma unroll
                for (int nt = 0; nt < 2; ++nt)
                    #pragma unroll
                    for (int s = 0; s < 2; ++s) {
                        bHn[nt][s] = *(const h8*)(xh + bD[nt][s] + nk);
                        bLn[nt][s] = *(const h8*)(xl + bD[nt][s] + nk);
                    }
            }
            h8 aH[2][2], aL[2][2];
            #pragma unroll
            for (int mt = 0; mt < 2; ++mt)
                #pragma unroll
                for (int s = 0; s < 2; ++s) {
                    aH[mt][s] = *(const h8*)&sA[co + offA[mt][s]];
                    aL[mt][s] = *(const h8*)&sA[co + 4096 + offA[mt][s]];
                }
            #pragma unroll
            for (int mt = 0; mt < 2; ++mt)
                #pragma unroll
                for (int nt = 0; nt < 2; ++nt)
                    #pragma unroll
                    for (int s = 0; s < 2; ++s) {
                        acc[mt][nt] = __builtin_amdgcn_mfma_f32_32x32x16_f16(
                            aH[mt][s], bHc[nt][s], acc[mt][nt], 0, 0, 0);
                        acc[mt][nt] = __builtin_amdgcn_mfma_f32_32x32x16_f16(
                            aH[mt][s], bLc[nt][s], acc[mt][nt], 0, 0, 0);
                        acc[mt][nt] = __builtin_amdgcn_mfma_f32_32x32x16_f16(
                            aL[mt][s], bHc[nt][s], acc[mt][nt], 0, 0, 0);
                    }
            __syncthreads();
            if (nk < DIM) {
                #pragma unroll
                for (int nt = 0; nt < 2; ++nt)
                    #pragma unroll
                    for (int s = 0; s < 2; ++s) {
                        bHc[nt][s] = bHn[nt][s];
                        bLc[nt][s] = bLn[nt][s];
                    }
            }
            co = cn;
        }
        #pragma unroll
        for (int mt = 0; mt < 2; ++mt)
            #pragma unroll
            for (int nt = 0; nt < 2; ++nt) {
                int col = m0 + wc * 64 + nt * 32 + r5;
                #pragma unroll
                for (int reg = 0; reg < 16; ++reg) {
                    int rl = (reg & 3) + 8 * (reg >> 2) + 4 * h;
                    int n = n0 + wr * 64 + mt * 32 + rl;
                    float val = acc[mt][nt][reg] + biasp[n];
                    val = fminf(fmaxf(val, -PI_F), PI_F);
                    bufph[(size_t)(n - NPAD) * M_TOT + col] = val;
                }
            }
    }
}

// ---------------------------------------------------------------------------
// Scan: per (k-tile of 32, b): cumsum inst_freq over t, spec = mag*e^{i phase},
// written TRANSPOSED to specT[m][KSPEC] f16. kt in 0..15 (bin 512 separate).
// ---------------------------------------------------------------------------
__global__ __launch_bounds__(256) void k_scan(
    const _Float16* __restrict__ mag, const float* __restrict__ iF,
    _Float16* __restrict__ specT) {
    __shared__ float sums[32][65];
    __shared__ _Float16 ta[256][32];
    __shared__ _Float16 tb[256][32];
    const int tid = threadIdx.x;
    const int r = tid & 31;
    const int sg = tid >> 5;
    const int kt = blockIdx.x;      // 0..15
    const int b = blockIdx.y;
    const int k = kt * 32 + r;
    const size_t base = (size_t)k * M_TOT + b * T_;

    #pragma unroll
    for (int ss = 0; ss < 8; ++ss) {
        int sub = sg * 8 + ss;
        const float* p = iF + base + sub * 32;
        float s = 0.f;
        #pragma unroll
        for (int i = 0; i < 32; i += 4) {
            float4 v = *(const float4*)(p + i);
            s += v.x + v.y + v.z + v.w;
        }
        sums[r][sub] = s;
    }
    __syncthreads();
    if (tid < 32) {
        float run = 0.f;
        for (int s = 0; s < 64; ++s) {
            float t = sums[tid][s];
            sums[tid][s] = run;
            run += t;
        }
    }
    __syncthreads();

    for (int c = 0; c < 8; ++c) {
        int tl0 = sg * 32;
        float run = sums[r][c * 8 + sg];
        const float* pf = iF + base + c * 256 + tl0;
        const _Float16* pm = mag + base + c * 256 + tl0;
        for (int i = 0; i < 32; ++i) {
            run += pf[i];
            float m = (float)pm[i];
            float sn, cs;
            __sincosf(run, &sn, &cs);   // |run| < ~200 rad; f32 reduce err ~1e-5
            ta[tl0 + i][r] = (_Float16)(m * cs);
            tb[tl0 + i][r] = (_Float16)(m * sn);
        }
        __syncthreads();
        size_t mrow = (size_t)b * T_ + c * 256 + tid;
        _Float16* dstA = specT + mrow * KSPEC + kt * 32;
        _Float16* dstB = specT + mrow * KSPEC + 528 + kt * 32;
        *(h8*)(dstA + 0)  = *(const h8*)&ta[tid][0];
        *(h8*)(dstA + 8)  = *(const h8*)&ta[tid][8];
        *(h8*)(dstA + 16) = *(const h8*)&ta[tid][16];
        *(h8*)(dstA + 24) = *(const h8*)&ta[tid][24];
        *(h8*)(dstB + 0)  = *(const h8*)&tb[tid][0];
        *(h8*)(dstB + 8)  = *(const h8*)&tb[tid][8];
        *(h8*)(dstB + 16) = *(const h8*)&tb[tid][16];
        *(h8*)(dstB + 24) = *(const h8*)&tb[tid][24];
        __syncthreads();
    }
}

// ---------------------------------------------------------------------------
// Bin 512: cumsum of clipped inst_freq + mag, write specT[:,512].
// One block per batch; exact f32 path. (sin term of bin 512 is identically 0)
// ---------------------------------------------------------------------------
__global__ __launch_bounds__(256) void k_spec512(
    const float* __restrict__ d512m, const float* __restrict__ d512p,
    const float* __restrict__ bm, const float* __restrict__ bp,
    _Float16* __restrict__ specT) {
    __shared__ float part[256];
    const int b = blockIdx.x;
    const int tid = threadIdx.x;
    const float bmv = bm[512], bpv = bp[512];
    const float* srcp = d512p + b * T_ + tid * 8;
    const float* srcm = d512m + b * T_ + tid * 8;
    float v[8];
    float s = 0.f;
    #pragma unroll
    for (int i = 0; i < 8; ++i) {
        float f = srcp[i] + bpv;
        f = fminf(fmaxf(f, -PI_F), PI_F);
        v[i] = f; s += f;
    }
    part[tid] = s;
    __syncthreads();
    if (tid == 0) {
        float run = 0.f;
        for (int i = 0; i < 256; ++i) { float t = part[i]; part[i] = run; run += t; }
    }
    __syncthreads();
    float run = part[tid];
    #pragma unroll
    for (int i = 0; i < 8; ++i) {
        run += v[i];
        float lm = fminf(fmaxf(srcm[i] + bmv, -10.f), 10.f);
        float mag = expf(lm);
        float sn, cs;
        __sincosf(run, &sn, &cs);
        size_t mrow = (size_t)b * T_ + tid * 8 + i;
        specT[mrow * KSPEC + 512] = (_Float16)(mag * cs);
    }
}

// ---------------------------------------------------------------------------
// GEMM2 (iDFT) v2: basisT (2 MB, L2-hot, reused by all m-blocks) via LDS
// double-buffer; specT (streamed once) read global->VGPR with 1-step reg
// prefetch. K=1056, 33 k-steps.
// ---------------------------------------------------------------------------
__global__ __launch_bounds__(256) void k_gemm_idft2(
    const _Float16* __restrict__ specT, const _Float16* __restrict__ basisT,
    _Float16* __restrict__ frames) {
    __shared__ _Float16 sB[2 * 4096];
    const int tid = threadIdx.x;
    const int lane = tid & 63;
    const int wv = tid >> 6;
    const int wr = wv >> 1, wc = wv & 1;
    const int h = lane >> 5, r5 = lane & 31;
    const int L = blockIdx.x;
    const int xcd = L & 7;
    const int idx = L >> 3;
    const int j_tile = idx & 7;
    const int m_tile = (idx >> 3) * 8 + xcd;
    const int j0 = j_tile * 128;
    const int m0 = m_tile * 128;

    // B (basisT) staging, pre-swizzled source
    const int cid0 = wv * 128 + lane, cid1 = cid0 + 64;
    const int ar0 = cid0 >> 2, g0 = (cid0 & 3) ^ xorf(ar0);
    const int ar1 = cid1 >> 2, g1 = (cid1 & 3) ^ xorf(ar1);
    const _Float16* gB0 = basisT + (size_t)(j0 + ar0) * KSPEC + g0 * 8;
    const _Float16* gB1 = basisT + (size_t)(j0 + ar1) * KSPEC + g1 * 8;
    const int pB = wv * 1024;

    const int xv = xorf(r5);
    int offB[2][2];
    #pragma unroll
    for (int nt = 0; nt < 2; ++nt)
        #pragma unroll
        for (int s = 0; s < 2; ++s)
            offB[nt][s] = (wc * 64 + nt * 32 + r5) * 32 + (((s << 1) | h) ^ xv) * 8;

    // A (specT) direct fragment addresses
    size_t aD[2][2];
    #pragma unroll
    for (int mt = 0; mt < 2; ++mt)
        #pragma unroll
        for (int s = 0; s < 2; ++s)
            aD[mt][s] = (size_t)(m0 + wr * 64 + mt * 32 + r5) * KSPEC
                        + (((s << 1) | h) << 3);

    fv16 acc[2][2];
    fv16 zero = {0,0,0,0,0,0,0,0,0,0,0,0,0,0,0,0};
    #pragma unroll
    for (int i = 0; i < 2; ++i)
        #pragma unroll
        for (int j = 0; j < 2; ++j) acc[i][j] = zero;

    h8 aHc[2][2], aHn[2][2];
    GLOAD_LDS16(gB0, sB + pB);
    GLOAD_LDS16(gB1, sB + pB + 512);
    #pragma unroll
    for (int mt = 0; mt < 2; ++mt)
        #pragma unroll
        for (int s = 0; s < 2; ++s)
            aHc[mt][s] = *(const h8*)(specT + aD[mt][s]);
    __syncthreads();
    int co = 0;
    for (int k0 = 0; k0 < KSPEC; k0 += 32) {
        const int nk = k0 + 32;
        const int cn = co ^ 4096;
        if (nk < KSPEC) {
            GLOAD_LDS16(gB0 + nk, sB + cn + pB);
            GLOAD_LDS16(gB1 + nk, sB + cn + pB + 512);
            #pragma unroll
            for (int mt = 0; mt < 2; ++mt)
                #pragma unroll
                for (int s = 0; s < 2; ++s)
                    aHn[mt][s] = *(const h8*)(specT + aD[mt][s] + nk);
        }
        h8 bf[2][2];
        #pragma unroll
        for (int nt = 0; nt < 2; ++nt)
            #pragma unroll
            for (int s = 0; s < 2; ++s)
                bf[nt][s] = *(const h8*)&sB[co + offB[nt][s]];
        #pragma unroll
        for (int mt = 0; mt < 2; ++mt)
            #pragma unroll
            for (int nt = 0; nt < 2; ++nt)
                #pragma unroll
                for (int s = 0; s < 2; ++s)
                    acc[mt][nt] = __builtin_amdgcn_mfma_f32_32x32x16_f16(
                        aHc[mt][s], bf[nt][s], acc[mt][nt], 0, 0, 0);
        __syncthreads();
        if (nk < KSPEC) {
            #pragma unroll
            for (int mt = 0; mt < 2; ++mt)
                #pragma unroll
                for (int s = 0; s < 2; ++s)
                    aHc[mt][s] = aHn[mt][s];
        }
        co = cn;
    }

    #pragma unroll
    for (int mt = 0; mt < 2; ++mt)
        #pragma unroll
        for (int nt = 0; nt < 2; ++nt) {
            int col = j0 + wc * 64 + nt * 32 + r5;
            #pragma unroll
            for (int reg = 0; reg < 16; ++reg) {
                int rl = (reg & 3) + 8 * (reg >> 2) + 4 * h;
                int m = m0 + wr * 64 + mt * 32 + rl;
                frames[((size_t)m << 10) + col] = (_Float16)acc[mt][nt][reg];
            }
        }
}

// ---------------------------------------------------------------------------
// OLA gather + envelope divide + clip
// ---------------------------------------------------------------------------
__global__ void k_ola(const _Float16* __restrict__ frames, float* __restrict__ out) {
    const int s_out = blockIdx.x * 256 + threadIdx.x;
    const int b = blockIdx.y;
    const int s = s_out + NFFT / 2;
    int t_lo = (s - (NFFT - HOP)) >> 8;
    if (t_lo < 0) t_lo = 0;
    int t_hi = s >> 8;
    if (t_hi > T_ - 1) t_hi = T_ - 1;
    float acc = 0.0f, env = 0.0f;
    for (int t = t_lo; t <= t_hi; ++t) {
        int j = s - (t << 8);
        acc += (float)frames[((size_t)(b * T_ + t) << 10) + j];
        float w = 0.5f * (1.0f - __cosf((float)j * (TWO_PI_F / NFFT)));
        env += w * w;
    }
    float r = acc / env;
    r = fminf(fmaxf(r, -1.0f), 1.0f);
    out[(size_t)b * OUT_LEN + s_out] = r;
}

// ---------------------------------------------------------------------------
extern "C" void kernel_launch(void* const* d_in, const int* in_sizes, int n_in,
                              void* d_out, int out_size, void* d_ws, size_t ws_size,
                              hipStream_t stream) {
    const float* x  = (const float*)d_in[0];
    const float* Wm = (const float*)d_in[1];
    const float* bm = (const float*)d_in[2];
    const float* Wp = (const float*)d_in[3];
    const float* bp = (const float*)d_in[4];
    float* out = (float*)d_out;

    char* ws = (char*)d_ws;
    const size_t OFF_MAG   = 0;                        // 512*32768*2   = 33,554,432
    const size_t OFF_D512  = 33554432;                 // 2*16*2048*4   = 262,144
    const size_t OFF_PH    = 41943040;                 // 512*32768*4   = 67,108,864
    const size_t OFF_XH    = 125829120;                // 67,108,864
    const size_t OFF_XL    = 192937984;                // 67,108,864
    const size_t OFF_WH    = 260046848;                //  2,621,440
    const size_t OFF_WL    = 262668288;                //  2,621,440
    const size_t OFF_BIAS  = 265289728;                //  5,120
    const size_t OFF_BASIS = 265294848;                //  2,162,688
    // Aliases: specT -> OFF_XH (xT dead after head gemm; spills into XL which
    // is also dead), frames -> OFF_MAG (mag/ph/d512 dead after scan/spec512).

    _Float16* bufmag = (_Float16*)(ws + OFF_MAG);
    float*    d512m  = (float*)(ws + OFF_D512);
    float*    d512p  = d512m + (size_t)B_ * T_;
    float*    bufph  = (float*)(ws + OFF_PH);
    _Float16* xh     = (_Float16*)(ws + OFF_XH);
    _Float16* xl     = (_Float16*)(ws + OFF_XL);
    _Float16* Wh     = (_Float16*)(ws + OFF_WH);
    _Float16* Wl     = (_Float16*)(ws + OFF_WL);
    float*    biasp  = (float*)(ws + OFF_BIAS);
    _Float16* basisT = (_Float16*)(ws + OFF_BASIS);
    _Float16* specT  = (_Float16*)(ws + OFF_XH);
    _Float16* frames = (_Float16*)(ws + OFF_MAG);

    k_zero512<<<dim3(2 * B_ * T_ / 256), 256, 0, stream>>>(d512m);
    k_convert_x<<<dim3(DIM / 64, T_ / 64, B_), 256, 0, stream>>>(x, Wm, Wp, xh, xl, d512m, d512p);
    k_pack_w<<<dim3(NROWS * DIM / 256), 256, 0, stream>>>(Wm, Wp, Wh, Wl);
    k_pack_bias<<<dim3((NROWS + 255) / 256), 256, 0, stream>>>(bm, bp, biasp);
    k_basisT<<<dim3((NFFT * KSPEC + 255) / 256), 256, 0, stream>>>(basisT);

    k_gemm_heads3<<<dim3(8 * (M_TOT / 128)), 256, 0, stream>>>(
        Wh, Wl, xh, xl, biasp, bufmag, bufph);
    k_scan<<<dim3(16, B_), 256, 0, stream>>>(bufmag, bufph, specT);
    k_spec512<<<dim3(B_), 256, 0, stream>>>(d512m, d512p, bm, bp, specT);
    k_gemm_idft2<<<dim3(8 * (M_TOT / 128)), 256, 0, stream>>>(specT, basisT, frames);
    k_ola<<<dim3(OUT_LEN / 256, B_), 256, 0, stream>>>(frames, out);
}

// Round 4
// 587.718 us; speedup vs baseline: 1.1997x; 1.1997x over previous
//
#include <hip/hip_runtime.h>
#include <math.h>

// Problem constants
constexpr int B_   = 16;
constexpr int DIM  = 1024;
constexpr int T_   = 2048;
constexpr int NFFT = 1024;
constexpr int HOP  = 256;
constexpr int NBINS = 513;
constexpr int M_TOT = B_ * T_;            // 32768
constexpr int OUT_LEN = HOP * (T_ - 1);   // 524032
constexpr int NPAD = 640;                 // padded rows per head region (W pack layout)
constexpr int NGEMM = 512;                // rows computed by head GEMMs (bin 512 separate)
constexpr int NROWS = 2 * NPAD;           // 1280 packed W rows
constexpr int KSPEC = 1056;               // spec/basis K (513 cos + pad + 512 sin + pad)
constexpr float TWO_PI_F = 6.28318530717958647692f;
constexpr float PI_F = 3.14159265358979323846f;

typedef _Float16 h8 __attribute__((ext_vector_type(8)));
typedef float fv16 __attribute__((ext_vector_type(16)));

#define GLOAD_LDS16(g, l) __builtin_amdgcn_global_load_lds(                  \
    (const __attribute__((address_space(1))) void*)(g),                      \
    (__attribute__((address_space(3))) void*)(l), 16, 0, 0)

// XOR swizzle of 16B groups within a 64B LDS row: kills the 8-way bank
// aliasing of row-stride-64B fragment reads.
__device__ __forceinline__ int xorf(int row) { return (row & 3) ^ ((row >> 2) & 3); }

// ---------------------------------------------------------------------------
// Zero the bin-512 accumulators (2 * B_*T_ floats, contiguous)
// ---------------------------------------------------------------------------
__global__ void k_zero512(float* __restrict__ p) {
    p[blockIdx.x * 256 + threadIdx.x] = 0.f;
}

// ---------------------------------------------------------------------------
// Convert x [b][k][t] f32 -> xT hi/lo [b][t][k] f16 (64x64 tile transpose).
// Fused: bin-512 partial dot products (exact f32) via atomicAdd.
// ---------------------------------------------------------------------------
__global__ __launch_bounds__(256) void k_convert_x(
    const float* __restrict__ x, const float* __restrict__ Wm,
    const float* __restrict__ Wp,
    _Float16* __restrict__ xh, _Float16* __restrict__ xl,
    float* __restrict__ d512m, float* __restrict__ d512p) {
    __shared__ float tile[64][65];
    const int tid = threadIdx.x;
    const int k0 = blockIdx.x * 64;
    const int t0 = blockIdx.y * 64;
    const int b  = blockIdx.z;
    {
        int kr = tid >> 2;
        int tq = (tid & 3) * 16;
        const float* src = x + ((size_t)(b * DIM + k0 + kr)) * T_ + t0 + tq;
        #pragma unroll
        for (int i = 0; i < 4; ++i) {
            float4 v = *(const float4*)(src + i * 4);
            tile[kr][tq + i * 4 + 0] = v.x;
            tile[kr][tq + i * 4 + 1] = v.y;
            tile[kr][tq + i * 4 + 2] = v.z;
            tile[kr][tq + i * 4 + 3] = v.w;
        }
    }
    __syncthreads();
    {
        int tr = tid >> 2;
        int kq = (tid & 3) * 16;
        const float* wm5 = Wm + (size_t)512 * DIM + k0 + kq;
        const float* wp5 = Wp + (size_t)512 * DIM + k0 + kq;
        _Float16 hv[16], lv[16];
        float pm = 0.f, pp = 0.f;
        #pragma unroll
        for (int i = 0; i < 16; ++i) {
            float w = tile[kq + i][tr];
            _Float16 h = (_Float16)w;
            hv[i] = h;
            lv[i] = (_Float16)(w - (float)h);
            pm += w * wm5[i];
            pp += w * wp5[i];
        }
        size_t base = ((size_t)(b * T_ + t0 + tr)) * DIM + k0 + kq;
        *(h8*)(xh + base)     = *(const h8*)&hv[0];
        *(h8*)(xh + base + 8) = *(const h8*)&hv[8];
        *(h8*)(xl + base)     = *(const h8*)&lv[0];
        *(h8*)(xl + base + 8) = *(const h8*)&lv[8];
        // reduce the 4 k-quarters for this t-row (adjacent lanes)
        pm += __shfl_xor(pm, 1); pm += __shfl_xor(pm, 2);
        pp += __shfl_xor(pp, 1); pp += __shfl_xor(pp, 2);
        if ((tid & 3) == 0) {
            atomicAdd(&d512m[b * T_ + t0 + tr], pm);
            atomicAdd(&d512p[b * T_ + t0 + tr], pp);
        }
    }
}

// ---------------------------------------------------------------------------
// Pack W: rows 0..512 = W_mag, 513..639 zero, 640..1152 = W_phase, rest zero
// ---------------------------------------------------------------------------
__global__ void k_pack_w(const float* __restrict__ Wm, const float* __restrict__ Wp,
                         _Float16* __restrict__ Wh, _Float16* __restrict__ Wl) {
    int idx = blockIdx.x * 256 + threadIdx.x;
    if (idx >= NROWS * DIM) return;
    int n = idx >> 10, k = idx & 1023;
    float w = 0.f;
    if (n < NBINS) w = Wm[(size_t)n * DIM + k];
    else if (n >= NPAD && n < NPAD + NBINS) w = Wp[(size_t)(n - NPAD) * DIM + k];
    _Float16 h = (_Float16)w;
    Wh[idx] = h;
    Wl[idx] = (_Float16)(w - (float)h);
}

__global__ void k_pack_bias(const float* __restrict__ bm, const float* __restrict__ bp,
                            float* __restrict__ biasp) {
    int n = blockIdx.x * 256 + threadIdx.x;
    if (n >= NROWS) return;
    float v = 0.f;
    if (n < NBINS) v = bm[n];
    else if (n >= NPAD && n < NPAD + NBINS) v = bp[n - NPAD];
    biasp[n] = v;
}

// ---------------------------------------------------------------------------
// basisT[j][r] f16, stride KSPEC. Includes 1/N, irfft weights, Hann window.
// ---------------------------------------------------------------------------
__global__ void k_basisT(_Float16* __restrict__ basisT) {
    int idx = blockIdx.x * 256 + threadIdx.x;
    if (idx >= NFFT * KSPEC) return;
    int j = idx / KSPEC;
    int r = idx - j * KSPEC;
    float win = 0.5f * (1.0f - __cosf((float)j * (TWO_PI_F / NFFT)));
    float val = 0.f;
    if (r < NBINS) {
        int k = r;
        int m = (k * j) & (NFFT - 1);
        float s, c;
        __sincosf((float)m * (TWO_PI_F / NFFT), &s, &c);
        float w = (k == 0 || k == NFFT / 2) ? 1.0f : 2.0f;
        val = w * (1.0f / NFFT) * c * win;
    } else if (r >= 528 && r < 1040) {
        int k = r - 528;
        int m = (k * j) & (NFFT - 1);
        float s, c;
        __sincosf((float)m * (TWO_PI_F / NFFT), &s, &c);
        val = -2.0f * (1.0f / NFFT) * s * win;
    }
    basisT[idx] = (_Float16)val;
}

// ---------------------------------------------------------------------------
// Mag GEMM: 1-pass hi*hi, epilogue exp(clip(.+b)) -> f16.
// 128x128 tile, BK=32, 2-phase LDS double-buffer (stage k+1 before compute k,
// one __syncthreads per k-step), coalesced global_load_lds staging,
// XCD swizzle, XOR LDS swizzle. LDS 32 KiB -> 5 blocks/CU.
// ---------------------------------------------------------------------------
__global__ __launch_bounds__(256) void k_gemm_mag4(
    const _Float16* __restrict__ Wh, const _Float16* __restrict__ xh,
    const float* __restrict__ biasp, _Float16* __restrict__ bufmag) {
    __shared__ _Float16 sm[2][8192];   // [buf][ A:0..4095 | B:4096..8191 ]
    const int tid = threadIdx.x;
    const int lane = tid & 63;
    const int wv = tid >> 6;
    const int wr = wv >> 1, wc = wv & 1;
    const int h = lane >> 5, r5 = lane & 31;
    const int L = blockIdx.x;
    const int xcd = L & 7;
    const int idx = L >> 3;
    const int n_tile = idx & 3;
    const int m_tile = (idx >> 2) * 8 + xcd;
    const int n0 = n_tile * 128;
    const int m0 = m_tile * 128;
    const int bb = m0 >> 11;
    const int t0 = m0 & (T_ - 1);
    const size_t xbase = ((size_t)(bb * T_ + t0)) * DIM;

    const int cid0 = wv * 128 + lane, cid1 = cid0 + 64;
    const int ar0 = cid0 >> 2, g0 = (cid0 & 3) ^ xorf(ar0);
    const int ar1 = cid1 >> 2, g1 = (cid1 & 3) ^ xorf(ar1);
    const _Float16* gA0 = Wh + ((size_t)(n0 + ar0) << 10) + g0 * 8;
    const _Float16* gA1 = Wh + ((size_t)(n0 + ar1) << 10) + g1 * 8;
    const _Float16* gB0 = xh + xbase + ((size_t)ar0 << 10) + g0 * 8;
    const _Float16* gB1 = xh + xbase + ((size_t)ar1 << 10) + g1 * 8;
    const int pW = wv * 1024;

    const int xv = xorf(r5);
    int offA[2][2], offB[2][2];
    #pragma unroll
    for (int mt = 0; mt < 2; ++mt)
        #pragma unroll
        for (int s = 0; s < 2; ++s) {
            offA[mt][s] = (wr * 64 + mt * 32 + r5) * 32 + (((s << 1) | h) ^ xv) * 8;
            offB[mt][s] = 4096 + (wc * 64 + mt * 32 + r5) * 32 + (((s << 1) | h) ^ xv) * 8;
        }

    fv16 acc[2][2];
    fv16 zero = {0,0,0,0,0,0,0,0,0,0,0,0,0,0,0,0};
    #pragma unroll
    for (int i = 0; i < 2; ++i)
        #pragma unroll
        for (int j = 0; j < 2; ++j) acc[i][j] = zero;

#define STAGE_MAG(BUF, K)                                          \
    do {                                                           \
        GLOAD_LDS16(gB0 + (K), &sm[BUF][4096 + pW]);               \
        GLOAD_LDS16(gB1 + (K), &sm[BUF][4096 + pW + 512]);         \
        GLOAD_LDS16(gA0 + (K), &sm[BUF][pW]);                      \
        GLOAD_LDS16(gA1 + (K), &sm[BUF][pW + 512]);                \
    } while (0)

#define COMPUTE_MAG(BUF)                                           \
    do {                                                           \
        h8 af[2][2], bf[2][2];                                     \
        _Pragma("unroll")                                          \
        for (int mt = 0; mt < 2; ++mt)                             \
            _Pragma("unroll")                                      \
            for (int s = 0; s < 2; ++s) {                          \
                af[mt][s] = *(const h8*)&sm[BUF][offA[mt][s]];     \
                bf[mt][s] = *(const h8*)&sm[BUF][offB[mt][s]];     \
            }                                                      \
        _Pragma("unroll")                                          \
        for (int mt = 0; mt < 2; ++mt)                             \
            _Pragma("unroll")                                      \
            for (int nt = 0; nt < 2; ++nt)                         \
                _Pragma("unroll")                                  \
                for (int s = 0; s < 2; ++s)                        \
                    acc[mt][nt] = __builtin_amdgcn_mfma_f32_32x32x16_f16( \
                        af[mt][s], bf[nt][s], acc[mt][nt], 0, 0, 0);      \
    } while (0)

    STAGE_MAG(0, 0);
    __syncthreads();
    for (int k0 = 0; k0 < DIM; k0 += 64) {
        STAGE_MAG(1, k0 + 32);
        COMPUTE_MAG(0);
        __syncthreads();
        if (k0 + 64 < DIM) STAGE_MAG(0, k0 + 64);
        COMPUTE_MAG(1);
        __syncthreads();
    }
#undef STAGE_MAG
#undef COMPUTE_MAG

    #pragma unroll
    for (int mt = 0; mt < 2; ++mt)
        #pragma unroll
        for (int nt = 0; nt < 2; ++nt) {
            int col = m0 + wc * 64 + nt * 32 + r5;
            #pragma unroll
            for (int reg = 0; reg < 16; ++reg) {
                int rl = (reg & 3) + 8 * (reg >> 2) + 4 * h;
                int n = n0 + wr * 64 + mt * 32 + rl;
                float val = acc[mt][nt][reg] + biasp[n];
                val = fminf(fmaxf(val, -10.f), 10.f);
                bufmag[(size_t)n * M_TOT + col] = (_Float16)expf(val);
            }
        }
}

// ---------------------------------------------------------------------------
// Phase GEMM: 3-pass hi/lo (hi*hi + hi*lo + lo*hi), epilogue clip -> f32.
// Same 2-phase double-buffer; LDS 64 KiB -> 2 blocks/CU (pipeline replaces
// the lost TLP; 24 MFMAs hide the staged-load latency per k-step).
// ---------------------------------------------------------------------------
__global__ __launch_bounds__(256) void k_gemm_ph4(
    const _Float16* __restrict__ Wh, const _Float16* __restrict__ Wl,
    const _Float16* __restrict__ xh, const _Float16* __restrict__ xl,
    const float* __restrict__ biasp, float* __restrict__ bufph) {
    __shared__ _Float16 sm[2][16384]; // [buf][Ah|Al|Bh|Bl] 4096 each
    const int tid = threadIdx.x;
    const int lane = tid & 63;
    const int wv = tid >> 6;
    const int wr = wv >> 1, wc = wv & 1;
    const int h = lane >> 5, r5 = lane & 31;
    const int L = blockIdx.x;
    const int xcd = L & 7;
    const int idx = L >> 3;
    const int n_tile = idx & 3;
    const int m_tile = (idx >> 2) * 8 + xcd;
    const int n0 = NPAD + n_tile * 128;
    const int m0 = m_tile * 128;
    const int bb = m0 >> 11;
    const int t0 = m0 & (T_ - 1);
    const size_t xbase = ((size_t)(bb * T_ + t0)) * DIM;

    const int cid0 = wv * 128 + lane, cid1 = cid0 + 64;
    const int ar0 = cid0 >> 2, g0 = (cid0 & 3) ^ xorf(ar0);
    const int ar1 = cid1 >> 2, g1 = (cid1 & 3) ^ xorf(ar1);
    const size_t a0 = ((size_t)(n0 + ar0) << 10) + g0 * 8;
    const size_t a1 = ((size_t)(n0 + ar1) << 10) + g1 * 8;
    const size_t b0 = xbase + ((size_t)ar0 << 10) + g0 * 8;
    const size_t b1 = xbase + ((size_t)ar1 << 10) + g1 * 8;
    const int pW = wv * 1024;

    const int xv = xorf(r5);
    int offA[2][2], offB[2][2];
    #pragma unroll
    for (int mt = 0; mt < 2; ++mt)
        #pragma unroll
        for (int s = 0; s < 2; ++s) {
            offA[mt][s] = (wr * 64 + mt * 32 + r5) * 32 + (((s << 1) | h) ^ xv) * 8;
            offB[mt][s] = 8192 + (wc * 64 + mt * 32 + r5) * 32 + (((s << 1) | h) ^ xv) * 8;
        }

    fv16 acc[2][2];
    fv16 zero = {0,0,0,0,0,0,0,0,0,0,0,0,0,0,0,0};
    #pragma unroll
    for (int i = 0; i < 2; ++i)
        #pragma unroll
        for (int j = 0; j < 2; ++j) acc[i][j] = zero;

#define STAGE_PH(BUF, K)                                               \
    do {                                                               \
        GLOAD_LDS16(xh + b0 + (K), &sm[BUF][8192 + pW]);               \
        GLOAD_LDS16(xh + b1 + (K), &sm[BUF][8192 + pW + 512]);         \
        GLOAD_LDS16(xl + b0 + (K), &sm[BUF][12288 + pW]);              \
        GLOAD_LDS16(xl + b1 + (K), &sm[BUF][12288 + pW + 512]);        \
        GLOAD_LDS16(Wh + a0 + (K), &sm[BUF][pW]);                      \
        GLOAD_LDS16(Wh + a1 + (K), &sm[BUF][pW + 512]);                \
        GLOAD_LDS16(Wl + a0 + (K), &sm[BUF][4096 + pW]);               \
        GLOAD_LDS16(Wl + a1 + (K), &sm[BUF][4096 + pW + 512]);         \
    } while (0)

#define COMPUTE_PH(BUF)                                                \
    do {                                                               \
        h8 aH[2][2], bH[2][2], aL[2][2], bL[2][2];                     \
        _Pragma("unroll")                                              \
        for (int mt = 0; mt < 2; ++mt)                                 \
            _Pragma("unroll")                                          \
            for (int s = 0; s < 2; ++s) {                              \
                aH[mt][s] = *(const h8*)&sm[BUF][offA[mt][s]];         \
                aL[mt][s] = *(const h8*)&sm[BUF][4096 + offA[mt][s]];  \
                bH[mt][s] = *(const h8*)&sm[BUF][offB[mt][s]];         \
                bL[mt][s] = *(const h8*)&sm[BUF][4096 + offB[mt][s]];  \
            }                                                          \
        _Pragma("unroll")                                              \
        for (int mt = 0; mt < 2; ++mt)                                 \
            _Pragma("unroll")                                          \
            for (int nt = 0; nt < 2; ++nt)                             \
                _Pragma("unroll")                                      \
                for (int s = 0; s < 2; ++s) {                          \
                    acc[mt][nt] = __builtin_amdgcn_mfma_f32_32x32x16_f16( \
                        aH[mt][s], bH[nt][s], acc[mt][nt], 0, 0, 0);      \
                    acc[mt][nt] = __builtin_amdgcn_mfma_f32_32x32x16_f16( \
                        aH[mt][s], bL[nt][s], acc[mt][nt], 0, 0, 0);      \
                    acc[mt][nt] = __builtin_amdgcn_mfma_f32_32x32x16_f16( \
                        aL[mt][s], bH[nt][s], acc[mt][nt], 0, 0, 0);      \
                }                                                      \
    } while (0)

    STAGE_PH(0, 0);
    __syncthreads();
    for (int k0 = 0; k0 < DIM; k0 += 64) {
        STAGE_PH(1, k0 + 32);
        COMPUTE_PH(0);
        __syncthreads();
        if (k0 + 64 < DIM) STAGE_PH(0, k0 + 64);
        COMPUTE_PH(1);
        __syncthreads();
    }
#undef STAGE_PH
#undef COMPUTE_PH

    #pragma unroll
    for (int mt = 0; mt < 2; ++mt)
        #pragma unroll
        for (int nt = 0; nt < 2; ++nt) {
            int col = m0 + wc * 64 + nt * 32 + r5;
            #pragma unroll
            for (int reg = 0; reg < 16; ++reg) {
                int rl = (reg & 3) + 8 * (reg >> 2) + 4 * h;
                int n = n0 + wr * 64 + mt * 32 + rl;
                float val = acc[mt][nt][reg] + biasp[n];
                val = fminf(fmaxf(val, -PI_F), PI_F);
                bufph[(size_t)(n - NPAD) * M_TOT + col] = val;
            }
        }
}

// ---------------------------------------------------------------------------
// Scan: per (k-tile of 32, b): cumsum inst_freq over t, spec = mag*e^{i phase},
// written TRANSPOSED to specT[m][KSPEC] f16. kt in 0..15 (bin 512 separate).
// ---------------------------------------------------------------------------
__global__ __launch_bounds__(256) void k_scan(
    const _Float16* __restrict__ mag, const float* __restrict__ iF,
    _Float16* __restrict__ specT) {
    __shared__ float sums[32][65];
    __shared__ _Float16 ta[256][32];
    __shared__ _Float16 tb[256][32];
    const int tid = threadIdx.x;
    const int r = tid & 31;
    const int sg = tid >> 5;
    const int kt = blockIdx.x;      // 0..15
    const int b = blockIdx.y;
    const int k = kt * 32 + r;
    const size_t base = (size_t)k * M_TOT + b * T_;

    #pragma unroll
    for (int ss = 0; ss < 8; ++ss) {
        int sub = sg * 8 + ss;
        const float* p = iF + base + sub * 32;
        float s = 0.f;
        #pragma unroll
        for (int i = 0; i < 32; i += 4) {
            float4 v = *(const float4*)(p + i);
            s += v.x + v.y + v.z + v.w;
        }
        sums[r][sub] = s;
    }
    __syncthreads();
    if (tid < 32) {
        float run = 0.f;
        for (int s = 0; s < 64; ++s) {
            float t = sums[tid][s];
            sums[tid][s] = run;
            run += t;
        }
    }
    __syncthreads();

    for (int c = 0; c < 8; ++c) {
        int tl0 = sg * 32;
        float run = sums[r][c * 8 + sg];
        const float* pf = iF + base + c * 256 + tl0;
        const _Float16* pm = mag + base + c * 256 + tl0;
        for (int i = 0; i < 32; ++i) {
            run += pf[i];
            float m = (float)pm[i];
            float sn, cs;
            __sincosf(run, &sn, &cs);   // |run| < ~200 rad; f32 reduce err ~1e-5
            ta[tl0 + i][r] = (_Float16)(m * cs);
            tb[tl0 + i][r] = (_Float16)(m * sn);
        }
        __syncthreads();
        size_t mrow = (size_t)b * T_ + c * 256 + tid;
        _Float16* dstA = specT + mrow * KSPEC + kt * 32;
        _Float16* dstB = specT + mrow * KSPEC + 528 + kt * 32;
        *(h8*)(dstA + 0)  = *(const h8*)&ta[tid][0];
        *(h8*)(dstA + 8)  = *(const h8*)&ta[tid][8];
        *(h8*)(dstA + 16) = *(const h8*)&ta[tid][16];
        *(h8*)(dstA + 24) = *(const h8*)&ta[tid][24];
        *(h8*)(dstB + 0)  = *(const h8*)&tb[tid][0];
        *(h8*)(dstB + 8)  = *(const h8*)&tb[tid][8];
        *(h8*)(dstB + 16) = *(const h8*)&tb[tid][16];
        *(h8*)(dstB + 24) = *(const h8*)&tb[tid][24];
        __syncthreads();
    }
}

// ---------------------------------------------------------------------------
// Bin 512: cumsum of clipped inst_freq + mag, write specT[:,512].
// One block per batch; exact f32 path. (sin term of bin 512 is identically 0)
// ---------------------------------------------------------------------------
__global__ __launch_bounds__(256) void k_spec512(
    const float* __restrict__ d512m, const float* __restrict__ d512p,
    const float* __restrict__ bm, const float* __restrict__ bp,
    _Float16* __restrict__ specT) {
    __shared__ float part[256];
    const int b = blockIdx.x;
    const int tid = threadIdx.x;
    const float bmv = bm[512], bpv = bp[512];
    const float* srcp = d512p + b * T_ + tid * 8;
    const float* srcm = d512m + b * T_ + tid * 8;
    float v[8];
    float s = 0.f;
    #pragma unroll
    for (int i = 0; i < 8; ++i) {
        float f = srcp[i] + bpv;
        f = fminf(fmaxf(f, -PI_F), PI_F);
        v[i] = f; s += f;
    }
    part[tid] = s;
    __syncthreads();
    if (tid == 0) {
        float run = 0.f;
        for (int i = 0; i < 256; ++i) { float t = part[i]; part[i] = run; run += t; }
    }
    __syncthreads();
    float run = part[tid];
    #pragma unroll
    for (int i = 0; i < 8; ++i) {
        run += v[i];
        float lm = fminf(fmaxf(srcm[i] + bmv, -10.f), 10.f);
        float mag = expf(lm);
        float sn, cs;
        __sincosf(run, &sn, &cs);
        size_t mrow = (size_t)b * T_ + tid * 8 + i;
        specT[mrow * KSPEC + 512] = (_Float16)(mag * cs);
    }
}

// ---------------------------------------------------------------------------
// GEMM2 (iDFT): frames[m][j] = sum_r specT[m][r]*basisT[j][r], K=1056 (33
// k-steps: 16 double-steps + 1 tail). 2-phase double-buffer, 32 KiB LDS.
// ---------------------------------------------------------------------------
__global__ __launch_bounds__(256) void k_gemm_idft3(
    const _Float16* __restrict__ specT, const _Float16* __restrict__ basisT,
    _Float16* __restrict__ frames) {
    __shared__ _Float16 sm[2][8192];   // [buf][ A:0..4095 | B:4096..8191 ]
    const int tid = threadIdx.x;
    const int lane = tid & 63;
    const int wv = tid >> 6;
    const int wr = wv >> 1, wc = wv & 1;
    const int h = lane >> 5, r5 = lane & 31;
    const int L = blockIdx.x;
    const int xcd = L & 7;
    const int idx = L >> 3;
    const int j_tile = idx & 7;
    const int m_tile = (idx >> 3) * 8 + xcd;
    const int j0 = j_tile * 128;
    const int m0 = m_tile * 128;

    const int cid0 = wv * 128 + lane, cid1 = cid0 + 64;
    const int ar0 = cid0 >> 2, g0 = (cid0 & 3) ^ xorf(ar0);
    const int ar1 = cid1 >> 2, g1 = (cid1 & 3) ^ xorf(ar1);
    const _Float16* gA0 = specT + (size_t)(m0 + ar0) * KSPEC + g0 * 8;
    const _Float16* gA1 = specT + (size_t)(m0 + ar1) * KSPEC + g1 * 8;
    const _Float16* gB0 = basisT + (size_t)(j0 + ar0) * KSPEC + g0 * 8;
    const _Float16* gB1 = basisT + (size_t)(j0 + ar1) * KSPEC + g1 * 8;
    const int pW = wv * 1024;

    const int xv = xorf(r5);
    int offA[2][2], offB[2][2];
    #pragma unroll
    for (int mt = 0; mt < 2; ++mt)
        #pragma unroll
        for (int s = 0; s < 2; ++s) {
            offA[mt][s] = (wr * 64 + mt * 32 + r5) * 32 + (((s << 1) | h) ^ xv) * 8;
            offB[mt][s] = 4096 + (wc * 64 + mt * 32 + r5) * 32 + (((s << 1) | h) ^ xv) * 8;
        }

    fv16 acc[2][2];
    fv16 zero = {0,0,0,0,0,0,0,0,0,0,0,0,0,0,0,0};
    #pragma unroll
    for (int i = 0; i < 2; ++i)
        #pragma unroll
        for (int j = 0; j < 2; ++j) acc[i][j] = zero;

#define STAGE_I(BUF, K)                                            \
    do {                                                           \
        GLOAD_LDS16(gA0 + (K), &sm[BUF][pW]);                      \
        GLOAD_LDS16(gA1 + (K), &sm[BUF][pW + 512]);                \
        GLOAD_LDS16(gB0 + (K), &sm[BUF][4096 + pW]);               \
        GLOAD_LDS16(gB1 + (K), &sm[BUF][4096 + pW + 512]);         \
    } while (0)

#define COMPUTE_I(BUF)                                             \
    do {                                                           \
        h8 af[2][2], bf[2][2];                                     \
        _Pragma("unroll")                                          \
        for (int mt = 0; mt < 2; ++mt)                             \
            _Pragma("unroll")                                      \
            for (int s = 0; s < 2; ++s) {                          \
                af[mt][s] = *(const h8*)&sm[BUF][offA[mt][s]];     \
                bf[mt][s] = *(const h8*)&sm[BUF][offB[mt][s]];     \
            }                                                      \
        _Pragma("unroll")                                          \
        for (int mt = 0; mt < 2; ++mt)                             \
            _Pragma("unroll")                                      \
            for (int nt = 0; nt < 2; ++nt)                         \
                _Pragma("unroll")                                  \
                for (int s = 0; s < 2; ++s)                        \
                    acc[mt][nt] = __builtin_amdgcn_mfma_f32_32x32x16_f16( \
                        af[mt][s], bf[nt][s], acc[mt][nt], 0, 0, 0);      \
    } while (0)

    STAGE_I(0, 0);
    __syncthreads();
    // 16 double-steps cover k=0..1023; tail step covers k=1024..1055.
    for (int k0 = 0; k0 < 1024; k0 += 64) {
        STAGE_I(1, k0 + 32);
        COMPUTE_I(0);
        __syncthreads();
        STAGE_I(0, k0 + 64);     // k0+64 <= 1024 < KSPEC always valid
        COMPUTE_I(1);
        __syncthreads();
    }
    COMPUTE_I(0);                // tail k=1024
#undef STAGE_I
#undef COMPUTE_I

    #pragma unroll
    for (int mt = 0; mt < 2; ++mt)
        #pragma unroll
        for (int nt = 0; nt < 2; ++nt) {
            int col = j0 + wc * 64 + nt * 32 + r5;
            #pragma unroll
            for (int reg = 0; reg < 16; ++reg) {
                int rl = (reg & 3) + 8 * (reg >> 2) + 4 * h;
                int m = m0 + wr * 64 + mt * 32 + rl;
                frames[((size_t)m << 10) + col] = (_Float16)acc[mt][nt][reg];
            }
        }
}

// ---------------------------------------------------------------------------
// OLA gather + envelope divide + clip
// ---------------------------------------------------------------------------
__global__ void k_ola(const _Float16* __restrict__ frames, float* __restrict__ out) {
    const int s_out = blockIdx.x * 256 + threadIdx.x;
    const int b = blockIdx.y;
    const int s = s_out + NFFT / 2;
    int t_lo = (s - (NFFT - HOP)) >> 8;
    if (t_lo < 0) t_lo = 0;
    int t_hi = s >> 8;
    if (t_hi > T_ - 1) t_hi = T_ - 1;
    float acc = 0.0f, env = 0.0f;
    for (int t = t_lo; t <= t_hi; ++t) {
        int j = s - (t << 8);
        acc += (float)frames[((size_t)(b * T_ + t) << 10) + j];
        float w = 0.5f * (1.0f - __cosf((float)j * (TWO_PI_F / NFFT)));
        env += w * w;
    }
    float r = acc / env;
    r = fminf(fmaxf(r, -1.0f), 1.0f);
    out[(size_t)b * OUT_LEN + s_out] = r;
}

// ---------------------------------------------------------------------------
extern "C" void kernel_launch(void* const* d_in, const int* in_sizes, int n_in,
                              void* d_out, int out_size, void* d_ws, size_t ws_size,
                              hipStream_t stream) {
    const float* x  = (const float*)d_in[0];
    const float* Wm = (const float*)d_in[1];
    const float* bm = (const float*)d_in[2];
    const float* Wp = (const float*)d_in[3];
    const float* bp = (const float*)d_in[4];
    float* out = (float*)d_out;

    char* ws = (char*)d_ws;
    const size_t OFF_MAG   = 0;                        // 512*32768*2   = 33,554,432
    const size_t OFF_D512  = 33554432;                 // 2*16*2048*4   = 262,144
    const size_t OFF_PH    = 41943040;                 // 512*32768*4   = 67,108,864
    const size_t OFF_XH    = 125829120;                // 67,108,864
    const size_t OFF_XL    = 192937984;                // 67,108,864
    const size_t OFF_WH    = 260046848;                //  2,621,440
    const size_t OFF_WL    = 262668288;                //  2,621,440
    const size_t OFF_BIAS  = 265289728;                //  5,120
    const size_t OFF_BASIS = 265294848;                //  2,162,688
    // Aliases: specT -> OFF_XH (xT dead after head gemms; spills into XL which
    // is also dead), frames -> OFF_MAG (mag/ph/d512 dead after scan/spec512).

    _Float16* bufmag = (_Float16*)(ws + OFF_MAG);
    float*    d512m  = (float*)(ws + OFF_D512);
    float*    d512p  = d512m + (size_t)B_ * T_;
    float*    bufph  = (float*)(ws + OFF_PH);
    _Float16* xh     = (_Float16*)(ws + OFF_XH);
    _Float16* xl     = (_Float16*)(ws + OFF_XL);
    _Float16* Wh     = (_Float16*)(ws + OFF_WH);
    _Float16* Wl     = (_Float16*)(ws + OFF_WL);
    float*    biasp  = (float*)(ws + OFF_BIAS);
    _Float16* basisT = (_Float16*)(ws + OFF_BASIS);
    _Float16* specT  = (_Float16*)(ws + OFF_XH);
    _Float16* frames = (_Float16*)(ws + OFF_MAG);

    k_zero512<<<dim3(2 * B_ * T_ / 256), 256, 0, stream>>>(d512m);
    k_convert_x<<<dim3(DIM / 64, T_ / 64, B_), 256, 0, stream>>>(x, Wm, Wp, xh, xl, d512m, d512p);
    k_pack_w<<<dim3(NROWS * DIM / 256), 256, 0, stream>>>(Wm, Wp, Wh, Wl);
    k_pack_bias<<<dim3((NROWS + 255) / 256), 256, 0, stream>>>(bm, bp, biasp);
    k_basisT<<<dim3((NFFT * KSPEC + 255) / 256), 256, 0, stream>>>(basisT);

    k_gemm_mag4<<<dim3(4 * (M_TOT / 128)), 256, 0, stream>>>(Wh, xh, biasp, bufmag);
    k_gemm_ph4<<<dim3(4 * (M_TOT / 128)), 256, 0, stream>>>(Wh, Wl, xh, xl, biasp, bufph);
    k_scan<<<dim3(16, B_), 256, 0, stream>>>(bufmag, bufph, specT);
    k_spec512<<<dim3(B_), 256, 0, stream>>>(d512m, d512p, bm, bp, specT);
    k_gemm_idft3<<<dim3(8 * (M_TOT / 128)), 256, 0, stream>>>(specT, basisT, frames);
    k_ola<<<dim3(OUT_LEN / 256, B_), 256, 0, stream>>>(frames, out);
}

// Round 5
// 559.864 us; speedup vs baseline: 1.2593x; 1.0498x over previous
//
#include <hip/hip_runtime.h>
#include <math.h>

// Problem constants
constexpr int B_   = 16;
constexpr int DIM  = 1024;
constexpr int T_   = 2048;
constexpr int NFFT = 1024;
constexpr int HOP  = 256;
constexpr int NBINS = 513;
constexpr int M_TOT = B_ * T_;            // 32768
constexpr int OUT_LEN = HOP * (T_ - 1);   // 524032
constexpr int NPAD = 640;                 // padded rows per head region (W pack layout)
constexpr int NGEMM = 512;                // rows computed by head GEMMs (bin 512 separate)
constexpr int NROWS = 2 * NPAD;           // 1280 packed W rows
constexpr int KSPEC = 1056;               // spec K layout (513 cos + pad + 512 sin + pad)
constexpr int KCS   = 544;                // per-half K for the symmetric iDFT (528 + pad)
constexpr int CSW   = 1280;               // CS output width: 5 C-tiles + 5 S-tiles
constexpr float TWO_PI_F = 6.28318530717958647692f;
constexpr float PI_F = 3.14159265358979323846f;

typedef _Float16 h8 __attribute__((ext_vector_type(8)));
typedef float fv16 __attribute__((ext_vector_type(16)));

#define GLOAD_LDS16(g, l) __builtin_amdgcn_global_load_lds(                  \
    (const __attribute__((address_space(1))) void*)(g),                      \
    (__attribute__((address_space(3))) void*)(l), 16, 0, 0)

// XOR swizzle of 16B groups within a 64B LDS row: kills the 8-way bank
// aliasing of row-stride-64B fragment reads.
__device__ __forceinline__ int xorf(int row) { return (row & 3) ^ ((row >> 2) & 3); }

// ---------------------------------------------------------------------------
// Zero the bin-512 accumulators (2 * B_*T_ floats, contiguous)
// ---------------------------------------------------------------------------
__global__ void k_zero512(float* __restrict__ p) {
    p[blockIdx.x * 256 + threadIdx.x] = 0.f;
}

// ---------------------------------------------------------------------------
// Convert x [b][k][t] f32 -> xT hi/lo [b][t][k] f16 (64x64 tile transpose).
// Fused: bin-512 partial dot products (exact f32) via atomicAdd.
// ---------------------------------------------------------------------------
__global__ __launch_bounds__(256) void k_convert_x(
    const float* __restrict__ x, const float* __restrict__ Wm,
    const float* __restrict__ Wp,
    _Float16* __restrict__ xh, _Float16* __restrict__ xl,
    float* __restrict__ d512m, float* __restrict__ d512p) {
    __shared__ float tile[64][65];
    const int tid = threadIdx.x;
    const int k0 = blockIdx.x * 64;
    const int t0 = blockIdx.y * 64;
    const int b  = blockIdx.z;
    {
        int kr = tid >> 2;
        int tq = (tid & 3) * 16;
        const float* src = x + ((size_t)(b * DIM + k0 + kr)) * T_ + t0 + tq;
        #pragma unroll
        for (int i = 0; i < 4; ++i) {
            float4 v = *(const float4*)(src + i * 4);
            tile[kr][tq + i * 4 + 0] = v.x;
            tile[kr][tq + i * 4 + 1] = v.y;
            tile[kr][tq + i * 4 + 2] = v.z;
            tile[kr][tq + i * 4 + 3] = v.w;
        }
    }
    __syncthreads();
    {
        int tr = tid >> 2;
        int kq = (tid & 3) * 16;
        const float* wm5 = Wm + (size_t)512 * DIM + k0 + kq;
        const float* wp5 = Wp + (size_t)512 * DIM + k0 + kq;
        _Float16 hv[16], lv[16];
        float pm = 0.f, pp = 0.f;
        #pragma unroll
        for (int i = 0; i < 16; ++i) {
            float w = tile[kq + i][tr];
            _Float16 h = (_Float16)w;
            hv[i] = h;
            lv[i] = (_Float16)(w - (float)h);
            pm += w * wm5[i];
            pp += w * wp5[i];
        }
        size_t base = ((size_t)(b * T_ + t0 + tr)) * DIM + k0 + kq;
        *(h8*)(xh + base)     = *(const h8*)&hv[0];
        *(h8*)(xh + base + 8) = *(const h8*)&hv[8];
        *(h8*)(xl + base)     = *(const h8*)&lv[0];
        *(h8*)(xl + base + 8) = *(const h8*)&lv[8];
        // reduce the 4 k-quarters for this t-row (adjacent lanes)
        pm += __shfl_xor(pm, 1); pm += __shfl_xor(pm, 2);
        pp += __shfl_xor(pp, 1); pp += __shfl_xor(pp, 2);
        if ((tid & 3) == 0) {
            atomicAdd(&d512m[b * T_ + t0 + tr], pm);
            atomicAdd(&d512p[b * T_ + t0 + tr], pp);
        }
    }
}

// ---------------------------------------------------------------------------
// Pack W: rows 0..512 = W_mag, 513..639 zero, 640..1152 = W_phase, rest zero
// ---------------------------------------------------------------------------
__global__ void k_pack_w(const float* __restrict__ Wm, const float* __restrict__ Wp,
                         _Float16* __restrict__ Wh, _Float16* __restrict__ Wl) {
    int idx = blockIdx.x * 256 + threadIdx.x;
    if (idx >= NROWS * DIM) return;
    int n = idx >> 10, k = idx & 1023;
    float w = 0.f;
    if (n < NBINS) w = Wm[(size_t)n * DIM + k];
    else if (n >= NPAD && n < NPAD + NBINS) w = Wp[(size_t)(n - NPAD) * DIM + k];
    _Float16 h = (_Float16)w;
    Wh[idx] = h;
    Wl[idx] = (_Float16)(w - (float)h);
}

__global__ void k_pack_bias(const float* __restrict__ bm, const float* __restrict__ bp,
                            float* __restrict__ biasp) {
    int n = blockIdx.x * 256 + threadIdx.x;
    if (n >= NROWS) return;
    float v = 0.f;
    if (n < NBINS) v = bm[n];
    else if (n >= NPAD && n < NPAD + NBINS) v = bp[n - NPAD];
    biasp[n] = v;
}

// ---------------------------------------------------------------------------
// basis2[c][r] f16, stride KCS=544. Symmetric iDFT basis.
//   c in [0,512]:    C col j=c:  basis = w_r/N * cos(2*pi*r*c/N) * win(c), r<=512
//   c in [513,639]:  zero (pad)
//   c in [640,1279]: S col j=c-640: basis = 2/N * sin(2*pi*r*j/N) * win(j), r<=511
// All other rows zero (kills specT pad garbage).
// ---------------------------------------------------------------------------
__global__ void k_basisT2(_Float16* __restrict__ basis2) {
    int idx = blockIdx.x * 256 + threadIdx.x;
    if (idx >= CSW * KCS) return;
    int c = idx / KCS;
    int r = idx - c * KCS;
    float val = 0.f;
    if (c < 640) {
        if (c <= 512 && r <= 512) {
            float win = 0.5f * (1.0f - __cosf((float)c * (TWO_PI_F / NFFT)));
            int m = (r * c) & (NFFT - 1);
            float s, cc;
            __sincosf((float)m * (TWO_PI_F / NFFT), &s, &cc);
            float w = (r == 0 || r == NFFT / 2) ? 1.0f : 2.0f;
            val = w * (1.0f / NFFT) * cc * win;
        }
    } else {
        int j = c - 640;
        if (r <= 511) {
            float win = 0.5f * (1.0f - __cosf((float)j * (TWO_PI_F / NFFT)));
            int m = (r * j) & (NFFT - 1);
            float s, cc;
            __sincosf((float)m * (TWO_PI_F / NFFT), &s, &cc);
            val = 2.0f * (1.0f / NFFT) * s * win;
        }
    }
    basis2[idx] = (_Float16)val;
}

// ---------------------------------------------------------------------------
// Mag GEMM: 1-pass hi*hi, epilogue exp(clip(.+b)) -> f16.
// 128x128 tile, BK=32, 2-phase LDS double-buffer, XCD + XOR swizzle.
// ---------------------------------------------------------------------------
__global__ __launch_bounds__(256) void k_gemm_mag4(
    const _Float16* __restrict__ Wh, const _Float16* __restrict__ xh,
    const float* __restrict__ biasp, _Float16* __restrict__ bufmag) {
    __shared__ _Float16 sm[2][8192];   // [buf][ A:0..4095 | B:4096..8191 ]
    const int tid = threadIdx.x;
    const int lane = tid & 63;
    const int wv = tid >> 6;
    const int wr = wv >> 1, wc = wv & 1;
    const int h = lane >> 5, r5 = lane & 31;
    const int L = blockIdx.x;
    const int xcd = L & 7;
    const int idx = L >> 3;
    const int n_tile = idx & 3;
    const int m_tile = (idx >> 2) * 8 + xcd;
    const int n0 = n_tile * 128;
    const int m0 = m_tile * 128;
    const int bb = m0 >> 11;
    const int t0 = m0 & (T_ - 1);
    const size_t xbase = ((size_t)(bb * T_ + t0)) * DIM;

    const int cid0 = wv * 128 + lane, cid1 = cid0 + 64;
    const int ar0 = cid0 >> 2, g0 = (cid0 & 3) ^ xorf(ar0);
    const int ar1 = cid1 >> 2, g1 = (cid1 & 3) ^ xorf(ar1);
    const _Float16* gA0 = Wh + ((size_t)(n0 + ar0) << 10) + g0 * 8;
    const _Float16* gA1 = Wh + ((size_t)(n0 + ar1) << 10) + g1 * 8;
    const _Float16* gB0 = xh + xbase + ((size_t)ar0 << 10) + g0 * 8;
    const _Float16* gB1 = xh + xbase + ((size_t)ar1 << 10) + g1 * 8;
    const int pW = wv * 1024;

    const int xv = xorf(r5);
    int offA[2][2], offB[2][2];
    #pragma unroll
    for (int mt = 0; mt < 2; ++mt)
        #pragma unroll
        for (int s = 0; s < 2; ++s) {
            offA[mt][s] = (wr * 64 + mt * 32 + r5) * 32 + (((s << 1) | h) ^ xv) * 8;
            offB[mt][s] = 4096 + (wc * 64 + mt * 32 + r5) * 32 + (((s << 1) | h) ^ xv) * 8;
        }

    fv16 acc[2][2];
    fv16 zero = {0,0,0,0,0,0,0,0,0,0,0,0,0,0,0,0};
    #pragma unroll
    for (int i = 0; i < 2; ++i)
        #pragma unroll
        for (int j = 0; j < 2; ++j) acc[i][j] = zero;

#define STAGE_MAG(BUF, K)                                          \
    do {                                                           \
        GLOAD_LDS16(gB0 + (K), &sm[BUF][4096 + pW]);               \
        GLOAD_LDS16(gB1 + (K), &sm[BUF][4096 + pW + 512]);         \
        GLOAD_LDS16(gA0 + (K), &sm[BUF][pW]);                      \
        GLOAD_LDS16(gA1 + (K), &sm[BUF][pW + 512]);                \
    } while (0)

#define COMPUTE_MAG(BUF)                                           \
    do {                                                           \
        h8 af[2][2], bf[2][2];                                     \
        _Pragma("unroll")                                          \
        for (int mt = 0; mt < 2; ++mt)                             \
            _Pragma("unroll")                                      \
            for (int s = 0; s < 2; ++s) {                          \
                af[mt][s] = *(const h8*)&sm[BUF][offA[mt][s]];     \
                bf[mt][s] = *(const h8*)&sm[BUF][offB[mt][s]];     \
            }                                                      \
        _Pragma("unroll")                                          \
        for (int mt = 0; mt < 2; ++mt)                             \
            _Pragma("unroll")                                      \
            for (int nt = 0; nt < 2; ++nt)                         \
                _Pragma("unroll")                                  \
                for (int s = 0; s < 2; ++s)                        \
                    acc[mt][nt] = __builtin_amdgcn_mfma_f32_32x32x16_f16( \
                        af[mt][s], bf[nt][s], acc[mt][nt], 0, 0, 0);      \
    } while (0)

    STAGE_MAG(0, 0);
    __syncthreads();
    for (int k0 = 0; k0 < DIM; k0 += 64) {
        STAGE_MAG(1, k0 + 32);
        COMPUTE_MAG(0);
        __syncthreads();
        if (k0 + 64 < DIM) STAGE_MAG(0, k0 + 64);
        COMPUTE_MAG(1);
        __syncthreads();
    }
#undef STAGE_MAG
#undef COMPUTE_MAG

    #pragma unroll
    for (int mt = 0; mt < 2; ++mt)
        #pragma unroll
        for (int nt = 0; nt < 2; ++nt) {
            int col = m0 + wc * 64 + nt * 32 + r5;
            #pragma unroll
            for (int reg = 0; reg < 16; ++reg) {
                int rl = (reg & 3) + 8 * (reg >> 2) + 4 * h;
                int n = n0 + wr * 64 + mt * 32 + rl;
                float val = acc[mt][nt][reg] + biasp[n];
                val = fminf(fmaxf(val, -10.f), 10.f);
                bufmag[(size_t)n * M_TOT + col] = (_Float16)expf(val);
            }
        }
}

// ---------------------------------------------------------------------------
// Phase GEMM: 3-pass hi/lo (hi*hi + hi*lo + lo*hi), epilogue clip -> f32.
// Same 2-phase double-buffer; LDS 64 KiB -> 2 blocks/CU.
// ---------------------------------------------------------------------------
__global__ __launch_bounds__(256) void k_gemm_ph4(
    const _Float16* __restrict__ Wh, const _Float16* __restrict__ Wl,
    const _Float16* __restrict__ xh, const _Float16* __restrict__ xl,
    const float* __restrict__ biasp, float* __restrict__ bufph) {
    __shared__ _Float16 sm[2][16384]; // [buf][Ah|Al|Bh|Bl] 4096 each
    const int tid = threadIdx.x;
    const int lane = tid & 63;
    const int wv = tid >> 6;
    const int wr = wv >> 1, wc = wv & 1;
    const int h = lane >> 5, r5 = lane & 31;
    const int L = blockIdx.x;
    const int xcd = L & 7;
    const int idx = L >> 3;
    const int n_tile = idx & 3;
    const int m_tile = (idx >> 2) * 8 + xcd;
    const int n0 = NPAD + n_tile * 128;
    const int m0 = m_tile * 128;
    const int bb = m0 >> 11;
    const int t0 = m0 & (T_ - 1);
    const size_t xbase = ((size_t)(bb * T_ + t0)) * DIM;

    const int cid0 = wv * 128 + lane, cid1 = cid0 + 64;
    const int ar0 = cid0 >> 2, g0 = (cid0 & 3) ^ xorf(ar0);
    const int ar1 = cid1 >> 2, g1 = (cid1 & 3) ^ xorf(ar1);
    const size_t a0 = ((size_t)(n0 + ar0) << 10) + g0 * 8;
    const size_t a1 = ((size_t)(n0 + ar1) << 10) + g1 * 8;
    const size_t b0 = xbase + ((size_t)ar0 << 10) + g0 * 8;
    const size_t b1 = xbase + ((size_t)ar1 << 10) + g1 * 8;
    const int pW = wv * 1024;

    const int xv = xorf(r5);
    int offA[2][2], offB[2][2];
    #pragma unroll
    for (int mt = 0; mt < 2; ++mt)
        #pragma unroll
        for (int s = 0; s < 2; ++s) {
            offA[mt][s] = (wr * 64 + mt * 32 + r5) * 32 + (((s << 1) | h) ^ xv) * 8;
            offB[mt][s] = 8192 + (wc * 64 + mt * 32 + r5) * 32 + (((s << 1) | h) ^ xv) * 8;
        }

    fv16 acc[2][2];
    fv16 zero = {0,0,0,0,0,0,0,0,0,0,0,0,0,0,0,0};
    #pragma unroll
    for (int i = 0; i < 2; ++i)
        #pragma unroll
        for (int j = 0; j < 2; ++j) acc[i][j] = zero;

#define STAGE_PH(BUF, K)                                               \
    do {                                                               \
        GLOAD_LDS16(xh + b0 + (K), &sm[BUF][8192 + pW]);               \
        GLOAD_LDS16(xh + b1 + (K), &sm[BUF][8192 + pW + 512]);         \
        GLOAD_LDS16(xl + b0 + (K), &sm[BUF][12288 + pW]);              \
        GLOAD_LDS16(xl + b1 + (K), &sm[BUF][12288 + pW + 512]);        \
        GLOAD_LDS16(Wh + a0 + (K), &sm[BUF][pW]);                      \
        GLOAD_LDS16(Wh + a1 + (K), &sm[BUF][pW + 512]);                \
        GLOAD_LDS16(Wl + a0 + (K), &sm[BUF][4096 + pW]);               \
        GLOAD_LDS16(Wl + a1 + (K), &sm[BUF][4096 + pW + 512]);         \
    } while (0)

#define COMPUTE_PH(BUF)                                                \
    do {                                                               \
        h8 aH[2][2], bH[2][2], aL[2][2], bL[2][2];                     \
        _Pragma("unroll")                                              \
        for (int mt = 0; mt < 2; ++mt)                                 \
            _Pragma("unroll")                                          \
            for (int s = 0; s < 2; ++s) {                              \
                aH[mt][s] = *(const h8*)&sm[BUF][offA[mt][s]];         \
                aL[mt][s] = *(const h8*)&sm[BUF][4096 + offA[mt][s]];  \
                bH[mt][s] = *(const h8*)&sm[BUF][offB[mt][s]];         \
                bL[mt][s] = *(const h8*)&sm[BUF][4096 + offB[mt][s]];  \
            }                                                          \
        _Pragma("unroll")                                              \
        for (int mt = 0; mt < 2; ++mt)                                 \
            _Pragma("unroll")                                          \
            for (int nt = 0; nt < 2; ++nt)                             \
                _Pragma("unroll")                                      \
                for (int s = 0; s < 2; ++s) {                          \
                    acc[mt][nt] = __builtin_amdgcn_mfma_f32_32x32x16_f16( \
                        aH[mt][s], bH[nt][s], acc[mt][nt], 0, 0, 0);      \
                    acc[mt][nt] = __builtin_amdgcn_mfma_f32_32x32x16_f16( \
                        aH[mt][s], bL[nt][s], acc[mt][nt], 0, 0, 0);      \
                    acc[mt][nt] = __builtin_amdgcn_mfma_f32_32x32x16_f16( \
                        aL[mt][s], bH[nt][s], acc[mt][nt], 0, 0, 0);      \
                }                                                      \
    } while (0)

    STAGE_PH(0, 0);
    __syncthreads();
    for (int k0 = 0; k0 < DIM; k0 += 64) {
        STAGE_PH(1, k0 + 32);
        COMPUTE_PH(0);
        __syncthreads();
        if (k0 + 64 < DIM) STAGE_PH(0, k0 + 64);
        COMPUTE_PH(1);
        __syncthreads();
    }
#undef STAGE_PH
#undef COMPUTE_PH

    #pragma unroll
    for (int mt = 0; mt < 2; ++mt)
        #pragma unroll
        for (int nt = 0; nt < 2; ++nt) {
            int col = m0 + wc * 64 + nt * 32 + r5;
            #pragma unroll
            for (int reg = 0; reg < 16; ++reg) {
                int rl = (reg & 3) + 8 * (reg >> 2) + 4 * h;
                int n = n0 + wr * 64 + mt * 32 + rl;
                float val = acc[mt][nt][reg] + biasp[n];
                val = fminf(fmaxf(val, -PI_F), PI_F);
                bufph[(size_t)(n - NPAD) * M_TOT + col] = val;
            }
        }
}

// ---------------------------------------------------------------------------
// Scan: per (k-tile of 32, b): cumsum inst_freq over t, spec = mag*e^{i phase},
// written TRANSPOSED to specT[m][KSPEC] f16. kt in 0..15 (bin 512 separate).
// ---------------------------------------------------------------------------
__global__ __launch_bounds__(256) void k_scan(
    const _Float16* __restrict__ mag, const float* __restrict__ iF,
    _Float16* __restrict__ specT) {
    __shared__ float sums[32][65];
    __shared__ _Float16 ta[256][32];
    __shared__ _Float16 tb[256][32];
    const int tid = threadIdx.x;
    const int r = tid & 31;
    const int sg = tid >> 5;
    const int kt = blockIdx.x;      // 0..15
    const int b = blockIdx.y;
    const int k = kt * 32 + r;
    const size_t base = (size_t)k * M_TOT + b * T_;

    #pragma unroll
    for (int ss = 0; ss < 8; ++ss) {
        int sub = sg * 8 + ss;
        const float* p = iF + base + sub * 32;
        float s = 0.f;
        #pragma unroll
        for (int i = 0; i < 32; i += 4) {
            float4 v = *(const float4*)(p + i);
            s += v.x + v.y + v.z + v.w;
        }
        sums[r][sub] = s;
    }
    __syncthreads();
    if (tid < 32) {
        float run = 0.f;
        for (int s = 0; s < 64; ++s) {
            float t = sums[tid][s];
            sums[tid][s] = run;
            run += t;
        }
    }
    __syncthreads();

    for (int c = 0; c < 8; ++c) {
        int tl0 = sg * 32;
        float run = sums[r][c * 8 + sg];
        const float* pf = iF + base + c * 256 + tl0;
        const _Float16* pm = mag + base + c * 256 + tl0;
        for (int i = 0; i < 32; ++i) {
            run += pf[i];
            float m = (float)pm[i];
            float sn, cs;
            __sincosf(run, &sn, &cs);   // |run| < ~200 rad; f32 reduce err ~1e-5
            ta[tl0 + i][r] = (_Float16)(m * cs);
            tb[tl0 + i][r] = (_Float16)(m * sn);
        }
        __syncthreads();
        size_t mrow = (size_t)b * T_ + c * 256 + tid;
        _Float16* dstA = specT + mrow * KSPEC + kt * 32;
        _Float16* dstB = specT + mrow * KSPEC + 528 + kt * 32;
        *(h8*)(dstA + 0)  = *(const h8*)&ta[tid][0];
        *(h8*)(dstA + 8)  = *(const h8*)&ta[tid][8];
        *(h8*)(dstA + 16) = *(const h8*)&ta[tid][16];
        *(h8*)(dstA + 24) = *(const h8*)&ta[tid][24];
        *(h8*)(dstB + 0)  = *(const h8*)&tb[tid][0];
        *(h8*)(dstB + 8)  = *(const h8*)&tb[tid][8];
        *(h8*)(dstB + 16) = *(const h8*)&tb[tid][16];
        *(h8*)(dstB + 24) = *(const h8*)&tb[tid][24];
        __syncthreads();
    }
}

// ---------------------------------------------------------------------------
// Bin 512: cumsum of clipped inst_freq + mag, write specT[:,512].
// ---------------------------------------------------------------------------
__global__ __launch_bounds__(256) void k_spec512(
    const float* __restrict__ d512m, const float* __restrict__ d512p,
    const float* __restrict__ bm, const float* __restrict__ bp,
    _Float16* __restrict__ specT) {
    __shared__ float part[256];
    const int b = blockIdx.x;
    const int tid = threadIdx.x;
    const float bmv = bm[512], bpv = bp[512];
    const float* srcp = d512p + b * T_ + tid * 8;
    const float* srcm = d512m + b * T_ + tid * 8;
    float v[8];
    float s = 0.f;
    #pragma unroll
    for (int i = 0; i < 8; ++i) {
        float f = srcp[i] + bpv;
        f = fminf(fmaxf(f, -PI_F), PI_F);
        v[i] = f; s += f;
    }
    part[tid] = s;
    __syncthreads();
    if (tid == 0) {
        float run = 0.f;
        for (int i = 0; i < 256; ++i) { float t = part[i]; part[i] = run; run += t; }
    }
    __syncthreads();
    float run = part[tid];
    #pragma unroll
    for (int i = 0; i < 8; ++i) {
        run += v[i];
        float lm = fminf(fmaxf(srcm[i] + bmv, -10.f), 10.f);
        float mag = expf(lm);
        float sn, cs;
        __sincosf(run, &sn, &cs);
        size_t mrow = (size_t)b * T_ + tid * 8 + i;
        specT[mrow * KSPEC + 512] = (_Float16)(mag * cs);
    }
}

// ---------------------------------------------------------------------------
// Symmetric iDFT GEMM: CS[m][c] = sum_r specT[m][Koff+r] * basis2[c][r],
// K=544 (17 steps). Tiles 0..4: C (Koff=0, cos half); 5..9: S (Koff=528,
// sin half). frames[j] = C(j)-S(j), frames[1024-j] = C(j)+S(j) recombined
// in k_ola. Half the FLOPs and half the specT traffic of the full iDFT.
// 2-phase double-buffer, 32 KiB LDS.
// ---------------------------------------------------------------------------
__global__ __launch_bounds__(256) void k_gemm_cs(
    const _Float16* __restrict__ specT, const _Float16* __restrict__ basis2,
    _Float16* __restrict__ CS) {
    __shared__ _Float16 sm[2][8192];   // [buf][ A:0..4095 | B:4096..8191 ]
    const int tid = threadIdx.x;
    const int lane = tid & 63;
    const int wv = tid >> 6;
    const int wr = wv >> 1, wc = wv & 1;
    const int h = lane >> 5, r5 = lane & 31;
    const int L = blockIdx.x;
    const int xcd = L & 7;
    const int idx = L >> 3;              // 0..319
    const int c_tile = idx % 10;         // 0..4 C, 5..9 S
    const int m_tile = (idx / 10) * 8 + xcd;
    const int c0 = c_tile * 128;
    const int m0 = m_tile * 128;
    const int Koff = (c_tile < 5) ? 0 : 528;

    const int cid0 = wv * 128 + lane, cid1 = cid0 + 64;
    const int ar0 = cid0 >> 2, g0 = (cid0 & 3) ^ xorf(ar0);
    const int ar1 = cid1 >> 2, g1 = (cid1 & 3) ^ xorf(ar1);
    const _Float16* gA0 = specT + (size_t)(m0 + ar0) * KSPEC + Koff + g0 * 8;
    const _Float16* gA1 = specT + (size_t)(m0 + ar1) * KSPEC + Koff + g1 * 8;
    const _Float16* gB0 = basis2 + (size_t)(c0 + ar0) * KCS + g0 * 8;
    const _Float16* gB1 = basis2 + (size_t)(c0 + ar1) * KCS + g1 * 8;
    const int pW = wv * 1024;

    const int xv = xorf(r5);
    int offA[2][2], offB[2][2];
    #pragma unroll
    for (int mt = 0; mt < 2; ++mt)
        #pragma unroll
        for (int s = 0; s < 2; ++s) {
            offA[mt][s] = (wr * 64 + mt * 32 + r5) * 32 + (((s << 1) | h) ^ xv) * 8;
            offB[mt][s] = 4096 + (wc * 64 + mt * 32 + r5) * 32 + (((s << 1) | h) ^ xv) * 8;
        }

    fv16 acc[2][2];
    fv16 zero = {0,0,0,0,0,0,0,0,0,0,0,0,0,0,0,0};
    #pragma unroll
    for (int i = 0; i < 2; ++i)
        #pragma unroll
        for (int j = 0; j < 2; ++j) acc[i][j] = zero;

#define STAGE_I(BUF, K)                                            \
    do {                                                           \
        GLOAD_LDS16(gA0 + (K), &sm[BUF][pW]);                      \
        GLOAD_LDS16(gA1 + (K), &sm[BUF][pW + 512]);                \
        GLOAD_LDS16(gB0 + (K), &sm[BUF][4096 + pW]);               \
        GLOAD_LDS16(gB1 + (K), &sm[BUF][4096 + pW + 512]);         \
    } while (0)

#define COMPUTE_I(BUF)                                             \
    do {                                                           \
        h8 af[2][2], bf[2][2];                                     \
        _Pragma("unroll")                                          \
        for (int mt = 0; mt < 2; ++mt)                             \
            _Pragma("unroll")                                      \
            for (int s = 0; s < 2; ++s) {                          \
                af[mt][s] = *(const h8*)&sm[BUF][offA[mt][s]];     \
                bf[mt][s] = *(const h8*)&sm[BUF][offB[mt][s]];     \
            }                                                      \
        _Pragma("unroll")                                          \
        for (int mt = 0; mt < 2; ++mt)                             \
            _Pragma("unroll")                                      \
            for (int nt = 0; nt < 2; ++nt)                         \
                _Pragma("unroll")                                  \
                for (int s = 0; s < 2; ++s)                        \
                    acc[mt][nt] = __builtin_amdgcn_mfma_f32_32x32x16_f16( \
                        af[mt][s], bf[nt][s], acc[mt][nt], 0, 0, 0);      \
    } while (0)

    STAGE_I(0, 0);
    __syncthreads();
    // 8 double-steps cover k=0..511; tail step covers k=512..543.
    for (int k0 = 0; k0 < 512; k0 += 64) {
        STAGE_I(1, k0 + 32);
        COMPUTE_I(0);
        __syncthreads();
        STAGE_I(0, k0 + 64);     // max stages k=512..543, valid (KCS=544)
        COMPUTE_I(1);
        __syncthreads();
    }
    COMPUTE_I(0);                // tail k=512
#undef STAGE_I
#undef COMPUTE_I

    #pragma unroll
    for (int mt = 0; mt < 2; ++mt)
        #pragma unroll
        for (int nt = 0; nt < 2; ++nt) {
            int col = c0 + wc * 64 + nt * 32 + r5;
            #pragma unroll
            for (int reg = 0; reg < 16; ++reg) {
                int rl = (reg & 3) + 8 * (reg >> 2) + 4 * h;
                int m = m0 + wr * 64 + mt * 32 + rl;
                CS[(size_t)m * CSW + col] = (_Float16)acc[mt][nt][reg];
            }
        }
}

// ---------------------------------------------------------------------------
// OLA gather + symmetric recombine + envelope divide + clip.
// frame[t][j] = CS[t][jj] + sgn*CS[t][640+jj], jj = j<=512 ? j : 1024-j,
// sgn = -1 for j<=512 else +1. (CS cols 0 and 640+512 are zero by basis.)
// ---------------------------------------------------------------------------
__global__ void k_ola(const _Float16* __restrict__ CS, float* __restrict__ out) {
    const int s_out = blockIdx.x * 256 + threadIdx.x;
    const int b = blockIdx.y;
    const int s = s_out + NFFT / 2;
    int t_lo = (s - (NFFT - HOP)) >> 8;
    if (t_lo < 0) t_lo = 0;
    int t_hi = s >> 8;
    if (t_hi > T_ - 1) t_hi = T_ - 1;
    float acc = 0.0f, env = 0.0f;
    for (int t = t_lo; t <= t_hi; ++t) {
        int j = s - (t << 8);
        int jj = (j <= 512) ? j : (NFFT - j);
        size_t row = (size_t)(b * T_ + t) * CSW;
        float c = (float)CS[row + jj];
        float sv = (float)CS[row + 640 + jj];
        acc += (j <= 512) ? (c - sv) : (c + sv);
        float w = 0.5f * (1.0f - __cosf((float)j * (TWO_PI_F / NFFT)));
        env += w * w;
    }
    float r = acc / env;
    r = fminf(fmaxf(r, -1.0f), 1.0f);
    out[(size_t)b * OUT_LEN + s_out] = r;
}

// ---------------------------------------------------------------------------
extern "C" void kernel_launch(void* const* d_in, const int* in_sizes, int n_in,
                              void* d_out, int out_size, void* d_ws, size_t ws_size,
                              hipStream_t stream) {
    const float* x  = (const float*)d_in[0];
    const float* Wm = (const float*)d_in[1];
    const float* bm = (const float*)d_in[2];
    const float* Wp = (const float*)d_in[3];
    const float* bp = (const float*)d_in[4];
    float* out = (float*)d_out;

    char* ws = (char*)d_ws;
    const size_t OFF_MAG   = 0;                        // 512*32768*2   = 33,554,432
    const size_t OFF_D512  = 33554432;                 // 2*16*2048*4   = 262,144
    const size_t OFF_PH    = 41943040;                 // 512*32768*4   = 67,108,864
    const size_t OFF_XH    = 125829120;                // 67,108,864
    const size_t OFF_XL    = 192937984;                // 67,108,864
    const size_t OFF_WH    = 260046848;                //  2,621,440
    const size_t OFF_WL    = 262668288;                //  2,621,440
    const size_t OFF_BIAS  = 265289728;                //  5,120
    const size_t OFF_BASIS = 265294848;                //  1,392,640 (basis2)
    // Aliases: specT -> OFF_XH (xT dead after head gemms; spills into XL which
    // is also dead). CS -> offset 0, 32768*1280*2 = 83,886,080 bytes: overlays
    // MAG+D512+PH regions, all dead once scan/spec512 have run.

    _Float16* bufmag = (_Float16*)(ws + OFF_MAG);
    float*    d512m  = (float*)(ws + OFF_D512);
    float*    d512p  = d512m + (size_t)B_ * T_;
    float*    bufph  = (float*)(ws + OFF_PH);
    _Float16* xh     = (_Float16*)(ws + OFF_XH);
    _Float16* xl     = (_Float16*)(ws + OFF_XL);
    _Float16* Wh     = (_Float16*)(ws + OFF_WH);
    _Float16* Wl     = (_Float16*)(ws + OFF_WL);
    float*    biasp  = (float*)(ws + OFF_BIAS);
    _Float16* basis2 = (_Float16*)(ws + OFF_BASIS);
    _Float16* specT  = (_Float16*)(ws + OFF_XH);
    _Float16* CS     = (_Float16*)(ws + 0);

    k_zero512<<<dim3(2 * B_ * T_ / 256), 256, 0, stream>>>(d512m);
    k_convert_x<<<dim3(DIM / 64, T_ / 64, B_), 256, 0, stream>>>(x, Wm, Wp, xh, xl, d512m, d512p);
    k_pack_w<<<dim3(NROWS * DIM / 256), 256, 0, stream>>>(Wm, Wp, Wh, Wl);
    k_pack_bias<<<dim3((NROWS + 255) / 256), 256, 0, stream>>>(bm, bp, biasp);
    k_basisT2<<<dim3((CSW * KCS + 255) / 256), 256, 0, stream>>>(basis2);

    k_gemm_mag4<<<dim3(4 * (M_TOT / 128)), 256, 0, stream>>>(Wh, xh, biasp, bufmag);
    k_gemm_ph4<<<dim3(4 * (M_TOT / 128)), 256, 0, stream>>>(Wh, Wl, xh, xl, biasp, bufph);
    k_scan<<<dim3(16, B_), 256, 0, stream>>>(bufmag, bufph, specT);
    k_spec512<<<dim3(B_), 256, 0, stream>>>(d512m, d512p, bm, bp, specT);
    k_gemm_cs<<<dim3(10 * (M_TOT / 128)), 256, 0, stream>>>(specT, basis2, CS);
    k_ola<<<dim3(OUT_LEN / 256, B_), 256, 0, stream>>>(CS, out);
}